// Round 1
// baseline (118.728 us; speedup 1.0000x reference)
//
#include <hip/hip_runtime.h>
#include <cstdint>

#define NB 2
#define LL 384
#define DIN 256
#define DE 128
#define NH 8
#define DH 32
#define HD 256          // NH*DH
#define SCALE 0.17677669529663687f

typedef __attribute__((ext_vector_type(8))) short bf16x8;
typedef __attribute__((ext_vector_type(4))) float f32x4;

static __device__ __forceinline__ unsigned short f2bf(float f) {
    uint32_t u = __builtin_bit_cast(uint32_t, f);
    u += 0x7FFF + ((u >> 16) & 1);          // RNE
    return (unsigned short)(u >> 16);
}
static __device__ __forceinline__ float bf2f(unsigned short u) {
    return __builtin_bit_cast(float, (uint32_t)u << 16);
}
static __device__ __forceinline__ float getf4(const float4& v, int k) {
    return k == 0 ? v.x : k == 1 ? v.y : k == 2 ? v.z : v.w;
}
static __device__ __forceinline__ bf16x8 pack8(const float4& a, const float4& b) {
    bf16x8 p;
    p[0]=(short)f2bf(a.x); p[1]=(short)f2bf(a.y); p[2]=(short)f2bf(a.z); p[3]=(short)f2bf(a.w);
    p[4]=(short)f2bf(b.x); p[5]=(short)f2bf(b.y); p[6]=(short)f2bf(b.z); p[7]=(short)f2bf(b.w);
    return p;
}

// ---------------- prep_we: We^T -> bf16 (HD x DE, n-major) ----------------
__global__ __launch_bounds__(128) void prep_we(const float* __restrict__ We,
                                               unsigned short* __restrict__ WeT) {
    const int n = blockIdx.x;    // 0..255
    const int k = threadIdx.x;   // 0..127
    WeT[n * DE + k] = f2bf(We[(size_t)k * HD + n]);
}

// ---------------- proj: q/k -> bf16, v/u -> fp32 ----------------
__global__ __launch_bounds__(256) void proj_kernel(
    const float* __restrict__ node,
    const float* __restrict__ Wq, const float* __restrict__ bq,
    const float* __restrict__ Wk, const float* __restrict__ bk,
    const float* __restrict__ Wv, const float* __restrict__ bv,
    const float* __restrict__ Wu, const float* __restrict__ bu,
    unsigned short* __restrict__ qb16, unsigned short* __restrict__ kb16,
    float* __restrict__ vb, float* __restrict__ ub)
{
    __shared__ __align__(16) float rows[4][DIN];
    const int t  = threadIdx.x;
    const int r0 = blockIdx.x * 4;

    #pragma unroll
    for (int r = 0; r < 4; ++r)
        rows[r][t] = node[(size_t)(r0 + r) * DIN + t];
    __syncthreads();

    float aq[4], ak[4], av[4], au[4];
    {
        const float vq = bq[t], vk = bk[t], vv = bv[t], vu = bu[t];
        #pragma unroll
        for (int r = 0; r < 4; ++r) { aq[r] = vq; ak[r] = vk; av[r] = vv; au[r] = vu; }
    }

    for (int f4 = 0; f4 < DIN / 4; ++f4) {
        float4 xv[4];
        #pragma unroll
        for (int r = 0; r < 4; ++r)
            xv[r] = *(const float4*)&rows[r][f4 * 4];
        #pragma unroll
        for (int k = 0; k < 4; ++k) {
            const int f = f4 * 4 + k;
            const float wq = Wq[(size_t)f * HD + t];
            const float wk = Wk[(size_t)f * HD + t];
            const float wv = Wv[(size_t)f * HD + t];
            const float wu = Wu[(size_t)f * HD + t];
            #pragma unroll
            for (int r = 0; r < 4; ++r) {
                const float x = getf4(xv[r], k);
                aq[r] += x * wq; ak[r] += x * wk; av[r] += x * wv; au[r] += x * wu;
            }
        }
    }

    #pragma unroll
    for (int r = 0; r < 4; ++r) {
        const size_t o = (size_t)(r0 + r) * HD + t;
        qb16[o] = f2bf(aq[r]); kb16[o] = f2bf(ak[r]);
        vb[o] = av[r]; ub[o] = au[r];
    }
}

// ---------------- vt: v (fp32, j-major) -> vT (bf16, col-major) ----------------
__global__ __launch_bounds__(256) void vt_kernel(const float* __restrict__ vb,
                                                 unsigned short* __restrict__ vT) {
    __shared__ float tile[64][65];
    int blk = blockIdx.x;
    const int b  = blk / 24; blk %= 24;
    const int jt = blk / 4;
    const int ct = blk % 4;
    const int j0 = jt * 64, c0 = ct * 64;
    const int t  = threadIdx.x;
    const int c  = t & 63, j4 = t >> 6;
    #pragma unroll
    for (int rr = 0; rr < 16; ++rr) {
        const int j = j4 + 4 * rr;
        tile[j][c] = vb[(size_t)(b * LL + j0 + j) * HD + c0 + c];
    }
    __syncthreads();
    const int jj = t & 63, c4 = t >> 6;
    #pragma unroll
    for (int rr = 0; rr < 16; ++rr) {
        const int cc = c4 + 4 * rr;
        vT[(size_t)(b * HD + c0 + cc) * LL + j0 + jj] = f2bf(tile[jj][cc]);
    }
}

// ---------------- qk: lpre[b,h,i,j] = SCALE*(q.k) - 1e9*(1-mask) ----------------
__global__ __launch_bounds__(256) void qk_kernel(
    const unsigned short* __restrict__ qb16, const unsigned short* __restrict__ kb16,
    const float* __restrict__ mask, float* __restrict__ logit_pre)
{
    int idx = blockIdx.x;
    const int jt = idx % 6; idx /= 6;
    const int it = idx % 6; idx /= 6;
    const int h  = idx % NH;
    const int b  = idx / NH;
    const int t    = threadIdx.x;
    const int lane = t & 63;
    const int w    = t >> 6;
    const int lid  = lane & 15;
    const int g    = lane >> 4;
    const int i0 = it * 64 + w * 16;
    const int j0 = jt * 64;

    const bf16x8 afr = *(const bf16x8*)&qb16[(size_t)(b * LL + i0 + lid) * HD + h * DH + g * 8];
    f32x4 acc[4];
    #pragma unroll
    for (int jj = 0; jj < 4; ++jj) {
        const bf16x8 bfrg = *(const bf16x8*)&kb16[(size_t)(b * LL + j0 + jj * 16 + lid) * HD + h * DH + g * 8];
        acc[jj] = __builtin_amdgcn_mfma_f32_16x16x32_bf16(afr, bfrg, (f32x4){0.f,0.f,0.f,0.f}, 0, 0, 0);
    }
    #pragma unroll
    for (int jj = 0; jj < 4; ++jj) {
        #pragma unroll
        for (int r = 0; r < 4; ++r) {
            const int i = i0 + 4 * g + r;
            const int j = j0 + jj * 16 + lid;
            const float lg = SCALE * acc[jj][r]
                           + (1.0f - mask[(size_t)(b * LL + i) * LL + j]) * -1e9f;
            logit_pre[((size_t)(b * NH + h) * LL + i) * LL + j] = lg;
        }
    }
}

// ---------------- qwe: qWe[b,i,h,c] = SCALE * sum_d q[b,i,h*32+d]*We[c,h*32+d] ----------------
// grid NB*LL blocks, 256 threads. thread: h = t>>5, c0 = (t&31)*4. Output bf16.
__global__ __launch_bounds__(256) void qwe_kernel(
    const unsigned short* __restrict__ qb16, const unsigned short* __restrict__ WeT,
    unsigned short* __restrict__ qWe)
{
    const int bi = blockIdx.x;
    const int t  = threadIdx.x;
    const int h  = t >> 5;
    const int c0 = (t & 31) * 4;

    float qv[32];
    const unsigned short* qp = &qb16[(size_t)bi * HD + h * DH];
    #pragma unroll
    for (int d = 0; d < 32; ++d) qv[d] = bf2f(qp[d]);

    float acc0 = 0.f, acc1 = 0.f, acc2 = 0.f, acc3 = 0.f;
    #pragma unroll
    for (int d = 0; d < 32; ++d) {
        const ushort4 wt = *(const ushort4*)&WeT[(size_t)(h * DH + d) * DE + c0];
        acc0 += qv[d] * bf2f(wt.x); acc1 += qv[d] * bf2f(wt.y);
        acc2 += qv[d] * bf2f(wt.z); acc3 += qv[d] * bf2f(wt.w);
    }
    unsigned short* o = &qWe[(size_t)bi * (NH * DE) + h * DE + c0];
    o[0] = f2bf(SCALE * acc0); o[1] = f2bf(SCALE * acc1);
    o[2] = f2bf(SCALE * acc2); o[3] = f2bf(SCALE * acc3);
}

// ---------------- att: logits (MFMA edge@qWe + qk) -> softmax -> att, in-place in lpre ----
// grid = NB*LL blocks (one per (b,i)), 512 threads = 8 waves. Wave w owns j in [48w,48w+48).
__global__ __launch_bounds__(512, 4) void att_kernel(
    const float* __restrict__ edge,            // (B,L,L,DE)
    const unsigned short* __restrict__ qWe,    // (B,L,NH,DE) bf16, SCALE folded
    float* __restrict__ lpre)                  // in: SCALE*qk+maskpen; out: att fp32
{
    __shared__ float red0[64], red1[64];
    const int t = threadIdx.x, lane = t & 63, w = t >> 6;
    const int lid = lane & 15, g = lane >> 4;
    const int bi = blockIdx.x, b = bi / LL, ii = bi % LL;
    const int J  = w * 48;
    const int hq = lid & 7;

    // B-frags: B[k=c][n=h] = qWe[h][c]  (lanes lid>=8 duplicate h, results ignored)
    bf16x8 bfr[4];
    const unsigned short* qwp = &qWe[(size_t)bi * (NH * DE) + hq * DE];
    #pragma unroll
    for (int kt = 0; kt < 4; ++kt)
        bfr[kt] = *(const bf16x8*)&qwp[kt * 32 + g * 8];

    // A-frags direct from global edge rows; acc[mt] = E(48x128) @ qWe^T(128x16)
    f32x4 acc[3];
    #pragma unroll
    for (int mt = 0; mt < 3; ++mt) {
        acc[mt] = (f32x4){0.f, 0.f, 0.f, 0.f};
        const float* ef = edge + ((size_t)bi * LL + J + mt * 16 + lid) * DE;
        #pragma unroll
        for (int kt = 0; kt < 4; ++kt) {
            const float4 x0 = *(const float4*)&ef[kt * 32 + g * 8];
            const float4 x1 = *(const float4*)&ef[kt * 32 + g * 8 + 4];
            acc[mt] = __builtin_amdgcn_mfma_f32_16x16x32_bf16(pack8(x0, x1), bfr[kt], acc[mt], 0, 0, 0);
        }
    }

    // logits: D row = 4g+r (j-local), col = lid (h)
    float lg[12];
    float* lrow = lpre + ((size_t)(b * NH + hq) * LL + ii) * LL;
    #pragma unroll
    for (int mt = 0; mt < 3; ++mt)
        #pragma unroll
        for (int r = 0; r < 4; ++r) {
            const int j = J + mt * 16 + g * 4 + r;
            lg[mt * 4 + r] = (lid < 8) ? (acc[mt][r] + lrow[j]) : -3e38f;
        }

    // block softmax, per h: reduce 12 regs, then g-lanes (xor 16,32), then waves via LDS
    float m = lg[0];
    #pragma unroll
    for (int k = 1; k < 12; ++k) m = fmaxf(m, lg[k]);
    m = fmaxf(m, __shfl_xor(m, 16));
    m = fmaxf(m, __shfl_xor(m, 32));
    if (lane < 8) red0[w * 8 + lane] = m;
    __syncthreads();
    float M = red0[hq];
    #pragma unroll
    for (int k = 1; k < 8; ++k) M = fmaxf(M, red0[k * 8 + hq]);

    float p[12], s = 0.f;
    #pragma unroll
    for (int k = 0; k < 12; ++k) { p[k] = __expf(lg[k] - M); s += p[k]; }
    s += __shfl_xor(s, 16); s += __shfl_xor(s, 32);
    if (lane < 8) red1[w * 8 + lane] = s;
    __syncthreads();
    float S = 0.f;
    #pragma unroll
    for (int k = 0; k < 8; ++k) S += red1[k * 8 + hq];
    const float inv = 1.0f / S;

    if (lid < 8) {
        #pragma unroll
        for (int mt = 0; mt < 3; ++mt)
            #pragma unroll
            for (int r = 0; r < 4; ++r)
                lrow[J + mt * 16 + g * 4 + r] = p[mt * 4 + r] * inv;
    }
}

// ---------------- pv: aE^T = E^T@att^T and av = vT@att^T via MFMA; epilogue aE@We ----
// grid = NB*LL blocks, 512 threads = 8 waves. Wave w: c-slice [16w,16w+16) for aE, head w for av.
#define TJ 64
#define NT (LL / TJ)    // 6
__global__ __launch_bounds__(512, 4) void pv_kernel(
    const float* __restrict__ edge,            // (B,L,L,DE)
    const float* __restrict__ att,             // (B,NH,L,L) fp32 (post-softmax)
    const unsigned short* __restrict__ vT,     // (B,HD,L) bf16
    const unsigned short* __restrict__ WeT,    // (HD,DE) bf16
    const float* __restrict__ ub,
    float* __restrict__ out)
{
    __shared__ __align__(16) unsigned short Es[2][TJ * DE];  // 2 x 16 KiB, linear row-major bf16
    __shared__ __align__(16) unsigned short atts[NH * LL];   // 6 KiB, att bf16 per head
    __shared__ float smA[NH * DE];                           // 4 KiB
    __shared__ float avs[HD];                                // 1 KiB

    const int t = threadIdx.x, lane = t & 63, w = t >> 6;
    const int lid = lane & 15, g = lane >> 4;
    const int bi = blockIdx.x, b = bi / LL, ii = bi % LL;
    const float* efbase = edge + (size_t)bi * LL * DE;

    // stage att row (head w) -> bf16 LDS, packed pairs
    {
        const float* ar = att + ((size_t)(b * NH + w) * LL + ii) * LL;
        #pragma unroll
        for (int k = 0; k < 3; ++k) {
            const int j2 = (lane + 64 * k) * 2;
            const float2 x = *(const float2*)&ar[j2];
            const unsigned int pk = ((unsigned int)f2bf(x.y) << 16) | (unsigned int)f2bf(x.x);
            *(unsigned int*)&atts[w * LL + j2] = pk;
        }
    }
    // stage E tile 0: thread covers chunks t and t+512 (sr=id>>4, ci=id&15)
    #pragma unroll
    for (int q = 0; q < 2; ++q) {
        const int id = t + q * 512, sr = id >> 4, ci = id & 15;
        const float* src = efbase + (size_t)sr * DE + ci * 8;
        const float4 x0 = ((const float4*)src)[0], x1 = ((const float4*)src)[1];
        *(bf16x8*)&Es[0][sr * DE + ci * 8] = pack8(x0, x1);
    }
    __syncthreads();

    f32x4 accE = (f32x4){0.f, 0.f, 0.f, 0.f};
    f32x4 accV[2];
    accV[0] = (f32x4){0.f, 0.f, 0.f, 0.f};
    accV[1] = (f32x4){0.f, 0.f, 0.f, 0.f};

    for (int tile = 0; tile < NT; ++tile) {
        const int j0  = tile * TJ;
        const int cur = tile & 1;
        const unsigned short* Ecur = Es[cur];
        const bool have_next = (tile + 1 < NT);
        float4 nx[2][2];
        if (have_next) {
            #pragma unroll
            for (int q = 0; q < 2; ++q) {
                const int id = t + q * 512, sr = id >> 4, ci = id & 15;
                const float* src = efbase + (size_t)(j0 + TJ + sr) * DE + ci * 8;
                nx[q][0] = ((const float4*)src)[0];
                nx[q][1] = ((const float4*)src)[1];
            }
        }
        #pragma unroll
        for (int kt = 0; kt < 2; ++kt) {
            const int jb = j0 + kt * 32;
            // B-frag: B[k=j][n=h] = att[h][jb + g*8+u]
            const bf16x8 bf = *(const bf16x8*)&atts[(lid & 7) * LL + jb + g * 8];
            // aE A-frag: A[m=c][k=j] = E[j][16w+lid]  (strided u16 reads, ~4-way ok)
            bf16x8 ae;
            #pragma unroll
            for (int u = 0; u < 8; ++u)
                ae[u] = (short)Ecur[(kt * 32 + g * 8 + u) * DE + 16 * w + lid];
            accE = __builtin_amdgcn_mfma_f32_16x16x32_bf16(ae, bf, accE, 0, 0, 0);
            // av A-frags: A[m=hd][k=j] = vT[hd][j], hd in [32w, 32w+32)
            #pragma unroll
            for (int mt = 0; mt < 2; ++mt) {
                const bf16x8 va = *(const bf16x8*)&vT[(size_t)(b * HD + w * DH + mt * 16 + lid) * LL + jb + g * 8];
                accV[mt] = __builtin_amdgcn_mfma_f32_16x16x32_bf16(va, bf, accV[mt], 0, 0, 0);
            }
        }
        if (have_next) {
            #pragma unroll
            for (int q = 0; q < 2; ++q) {
                const int id = t + q * 512, sr = id >> 4, ci = id & 15;
                *(bf16x8*)&Es[cur ^ 1][sr * DE + ci * 8] = pack8(nx[q][0], nx[q][1]);
            }
        }
        __syncthreads();   // next-buffer writes visible; this buffer's reads done
    }

    // scatter aE^T (row=4g+r -> c=16w+4g+r, col=lid -> h) and av (col lid==w) to LDS
    if (lid < 8) {
        #pragma unroll
        for (int r = 0; r < 4; ++r)
            smA[lid * DE + 16 * w + 4 * g + r] = accE[r];
    }
    if (lid == w) {
        #pragma unroll
        for (int mt = 0; mt < 2; ++mt)
            #pragma unroll
            for (int r = 0; r < 4; ++r)
                avs[w * DH + mt * 16 + 4 * g + r] = accV[mt][r];
    }
    __syncthreads();

    // epilogue: out[hd] = u + av + sum_c aE[h,c]*We[c,hd]
    if (lane < 32) {
        const int hd = w * DH + lane;
        float o = ub[(size_t)bi * HD + hd] + avs[hd];
        const unsigned short* wrow = &WeT[(size_t)hd * DE];
        const float* sa = &smA[w * DE];
        #pragma unroll
        for (int c = 0; c < DE; c += 4) {
            const ushort4 wt = *(const ushort4*)&wrow[c];
            o += sa[c]     * bf2f(wt.x);
            o += sa[c + 1] * bf2f(wt.y);
            o += sa[c + 2] * bf2f(wt.z);
            o += sa[c + 3] * bf2f(wt.w);
        }
        out[(size_t)bi * HD + hd] = o;
    }
}

extern "C" void kernel_launch(void* const* d_in, const int* in_sizes, int n_in,
                              void* d_out, int out_size, void* d_ws, size_t ws_size,
                              hipStream_t stream) {
    const float* node = (const float*)d_in[0];
    const float* edge = (const float*)d_in[1];
    const float* mask = (const float*)d_in[2];
    const float* Wq   = (const float*)d_in[3];
    const float* bq   = (const float*)d_in[4];
    const float* Wk   = (const float*)d_in[5];
    const float* bk   = (const float*)d_in[6];
    const float* Wv   = (const float*)d_in[7];
    const float* bv   = (const float*)d_in[8];
    const float* We   = (const float*)d_in[9];
    const float* Wu   = (const float*)d_in[10];
    const float* bu   = (const float*)d_in[11];
    float* out = (float*)d_out;

    const size_t rowsz = (size_t)NB * LL * HD;            // 196608
    float* ws   = (float*)d_ws;
    float* vb   = ws;
    float* ubuf = vb + rowsz;
    float* lpre = ubuf + rowsz;                           // NB*NH*LL*LL = 2359296
    unsigned short* us   = (unsigned short*)(lpre + (size_t)NB * NH * LL * LL);
    unsigned short* WeT  = us;                            // HD*DE = 32768
    unsigned short* qb16 = WeT + (size_t)HD * DE;
    unsigned short* kb16 = qb16 + rowsz;
    unsigned short* vT   = kb16 + rowsz;
    unsigned short* qWeB = vT + rowsz;                    // NB*LL*NH*DE = 786432

    hipLaunchKernelGGL(prep_we, dim3(HD), dim3(DE), 0, stream, We, WeT);
    hipLaunchKernelGGL(proj_kernel, dim3(NB * LL / 4), dim3(256), 0, stream,
                       node, Wq, bq, Wk, bk, Wv, bv, Wu, bu, qb16, kb16, vb, ubuf);
    hipLaunchKernelGGL(vt_kernel, dim3(NB * (LL / 64) * (HD / 64)), dim3(256), 0, stream,
                       vb, vT);
    hipLaunchKernelGGL(qk_kernel, dim3(NB * NH * (LL / 64) * (LL / 64)), dim3(256), 0, stream,
                       qb16, kb16, mask, lpre);
    hipLaunchKernelGGL(qwe_kernel, dim3(NB * LL), dim3(256), 0, stream,
                       qb16, WeT, qWeB);
    hipLaunchKernelGGL(att_kernel, dim3(NB * LL), dim3(512), 0, stream,
                       edge, qWeB, lpre);
    hipLaunchKernelGGL(pv_kernel, dim3(NB * LL), dim3(512), 0, stream,
                       edge, lpre, vT, WeT, ubuf, out);
}